// Round 6
// baseline (738.435 us; speedup 1.0000x reference)
//
#include <hip/hip_runtime.h>
#include <cstdint>
#include <cstddef>

// ---------------------------------------------------------------------------
// NaiveSDPA: out[n,s,v] = softmax(Q·K^T / 8 + mask) · V ; f32 I/O, bf16 MFMA.
// v11 = v10 (8 waves x 16q, 48 VGPR, role-split staging) + KV-split x2.
// r5 diagnosis: v10's occupancy ceiling was its own grid (512 blocks = exactly
// 2/CU); at VGPR=48 (<=64 tier), LDS 35.8KB and 512 thr, the HW allows
// 4 blocks/CU = 32 waves/CU. Reinstate the r2-verified KV-split + combine:
// grid (32,16,2) = 1024 blocks -> 4 blocks/CU, each half writes unnormalized
// acc + ones-MFMA row-sum l to workspace; elementwise pass combines.
// Also: two VALU trims on the QK->exp critical path:
//   - Q pre-scaled by 0.125*LOG2E at bf16 cast -> exp arg = fmaf(mk,LOG2E,c)
//     (one op, was fma+mul; same bf16 rounding class, softmax scale-invariant)
//   - hoisted K-frag base + 4-entry V-slot table (slot=(S0+4((h+nt)&3))&15)
//     -> ds addresses become base+imm / base+1add, removing rederived math.
// launch_bounds(512,8): budget 64, natural ~53 -> no cram -> no spill.
// Tripwires: WRITE_SIZE ~49MB (partials+out); GBs = spills. Occupancy ~80.
// ---------------------------------------------------------------------------

typedef __attribute__((ext_vector_type(8))) short short8;
typedef __attribute__((ext_vector_type(4))) short short4v;
typedef __attribute__((ext_vector_type(4))) float f32x4;
typedef __attribute__((ext_vector_type(4))) unsigned int uint4v;
typedef __attribute__((ext_vector_type(2))) unsigned int uint2v;

#define DEV __device__ __forceinline__

constexpr int N_B   = 16;
constexpr int S_Q   = 4096;
constexpr int S_KV  = 4096;
constexpr int DH    = 64;
constexpr int BQ    = 128;         // q rows per block (8 waves x 16)
constexpr int BK    = 64;
constexpr int ITERS = S_KV / BK;   // 64
constexpr int KSTR  = 72;          // shorts/row: 144B (skew 4 dwords)
constexpr int VSTR  = 68;          // shorts/row: 136B (16 slots + 4 pad)

#define LOG2E 1.44269504088896340736f
#define QSCALE (0.125f * 1.44269504088896340736f)   // fold /8 and log2e into Q

DEV unsigned short f2bf(float f) {           // RNE f32 -> bf16
  union { float f; unsigned int i; } x; x.f = f;
  unsigned int r = x.i + 0x7FFFu + ((x.i >> 16) & 1u);
  return (unsigned short)(r >> 16);
}

#if __has_builtin(__builtin_amdgcn_cvt_pk_bf16_f32)
typedef __attribute__((ext_vector_type(2))) __bf16 bf16x2v;
DEV unsigned int packrne(float a, float b) {   // bf16(a) lo | bf16(b) hi, RNE
  union { bf16x2v v; unsigned int u; } x;
  x.v = __builtin_amdgcn_cvt_pk_bf16_f32(a, b);
  return x.u;
}
#else
DEV unsigned int packrne(float a, float b) {
  union { float f; unsigned int u; } ua, ub; ua.f = a; ub.f = b;
  unsigned int ra = ua.u + 0x7FFFu + ((ua.u >> 16) & 1u);
  unsigned int rb = ub.u + 0x7FFFu + ((ub.u >> 16) & 1u);
  return __builtin_amdgcn_perm(rb, ra, 0x07060302u);
}
#endif

DEV f32x4 mfma16(short4v a, short4v b, f32x4 c) {
#if __has_builtin(__builtin_amdgcn_mfma_f32_16x16x16bf16_1k)
  return __builtin_amdgcn_mfma_f32_16x16x16bf16_1k(a, b, c, 0, 0, 0);
#elif __has_builtin(__builtin_amdgcn_mfma_f32_16x16x16_bf16)
  return __builtin_amdgcn_mfma_f32_16x16x16_bf16(a, b, c, 0, 0, 0);
#else
  asm volatile("v_mfma_f32_16x16x16_bf16 %0, %1, %2, %0\n\ts_nop 7\n\ts_nop 7"
               : "+v"(c) : "v"(a), "v"(b));
  return c;
#endif
}

// stage K tile (256 stager threads): thread tS owns 16B chunks
// (r=tS>>3, c=tS&7) and (r+32, c). L = {row r: lo,hi ; row r+32: lo,hi}.
DEV void stageK(unsigned short* buf, const f32x4* L, int tS) {
  const int r0 = tS >> 3, c = tS & 7;
  uint4v d0, d1;
  d0[0] = packrne(L[0][0], L[0][1]); d0[1] = packrne(L[0][2], L[0][3]);
  d0[2] = packrne(L[1][0], L[1][1]); d0[3] = packrne(L[1][2], L[1][3]);
  d1[0] = packrne(L[2][0], L[2][1]); d1[1] = packrne(L[2][2], L[2][3]);
  d1[2] = packrne(L[3][0], L[3][1]); d1[3] = packrne(L[3][2], L[3][3]);
  *(uint4v*)&buf[r0 * KSTR + c * 8]        = d0;
  *(uint4v*)&buf[(r0 + 32) * KSTR + c * 8] = d1;
}

// stage V^T (256 stager threads): thread tS loaded L[i] =
// V[kv=4*(tS>>4)+i][4*(tS&15)..+3] (coalesced per 16-lane phase). Writes
// chunk a=tS>>4 of vcol=4x+j (x=tS&15) at slot (a+x)&15: conflict-free.
DEV void stageV(unsigned short* buf, const f32x4* L, int tS) {
  const int a = tS >> 4;          // kv-chunk
  const int x = tS & 15;          // vcol>>2
  const int slot = (a + x) & 15;
#pragma unroll
  for (int j = 0; j < 4; ++j) {
    uint2v d;
    d[0] = packrne(L[0][j], L[1][j]);
    d[1] = packrne(L[2][j], L[3][j]);
    *(uint2v*)&buf[(x * 4 + j) * VSTR + slot * 4] = d;
  }
}

__global__ __launch_bounds__(512, 8)
void sdpa_fwd(const float* __restrict__ Qg,
              const float* __restrict__ Kg,
              const float* __restrict__ Vg,
              const float* __restrict__ Mg,
              float* __restrict__ Ob,    // Og (finalize) or ws acc base
              float* __restrict__ Lb,    // nullptr (finalize) or ws l base
              int nIter)
{
  __shared__ __align__(16) unsigned short ldsK[2][BK * KSTR];  // 2 x 9216 B
  __shared__ __align__(16) unsigned short ldsV[2][DH * VSTR];  // 2 x 8704 B

  const int n    = blockIdx.y;
  const int q0   = blockIdx.x * BQ;
  const int z    = blockIdx.z;                   // kv half
  const size_t kvbase = (size_t)z * (size_t)nIter * BK;
  const int t    = threadIdx.x;
  const int w    = t >> 6;          // wave 0..7: owns q rows q0+16w..+15
  const int lane = t & 63;
  const int l15  = lane & 15;
  const int quad = lane >> 4;
  const int qrow = q0 + w * 16 + l15;

  // ---- Q B-frags, pre-scaled by 0.125*log2e (exact softmax invariance;
  // same bf16 rounding class as unscaled cast)
  short8 qf0, qf1;
  {
    const float* qp = Qg + ((size_t)n * S_Q + (size_t)qrow) * DH + quad * 8;
#pragma unroll
    for (int j = 0; j < 8; ++j) {
      qf0[j] = (short)f2bf(qp[j] * QSCALE);
      qf1[j] = (short)f2bf(qp[32 + j] * QSCALE);
    }
  }

  // ---- staging role: waves 0-3 stage K, waves 4-7 stage V (wave-uniform)
  const bool isK = (w < 4);
  const int  tS  = t & 255;
  const float* sgp =
      isK ? Kg + ((size_t)n * S_KV + kvbase + (size_t)(tS >> 3)) * DH
              + (tS & 7) * 8
          : Vg + ((size_t)n * S_KV + kvbase + (size_t)(tS >> 4) * 4) * DH
              + (tS & 15) * 4;

  const float* mrow = Mg + (size_t)qrow * S_KV + kvbase + quad * 4;

  // ---- precomputed V-slot table: slot=(S0+4((h+nt)&3))&15, S0=quad+(l15>>2)
  // vf addr (shorts) = l15*VSTR + nt*16*VSTR (imm) + s4[(h+nt)&3]
  int s4[4];
  {
    const int S0 = quad + (l15 >> 2);
#pragma unroll
    for (int m = 0; m < 4; ++m) s4[m] = ((S0 + 4 * m) & 15) * 4;
  }

  // ---- O^T accumulators (C-layout: row v=16nt+quad*4+r, col q=l15)
  f32x4 acc[4];
#pragma unroll
  for (int nt = 0; nt < 4; ++nt)
#pragma unroll
    for (int r = 0; r < 4; ++r) acc[nt][r] = 0.0f;

  // ---- l accumulator via ones-MFMA (all rows equal; read [0] at the end)
  f32x4 ls = {0.f, 0.f, 0.f, 0.f};
  const short4v onesf = {(short)0x3F80, (short)0x3F80,
                         (short)0x3F80, (short)0x3F80};  // bf16 1.0

  // ---- prologue: load + stage tile 0 (role-split)
  {
    f32x4 L[4];
    if (isK) {
      L[0] = *(const f32x4*)(sgp);
      L[1] = *(const f32x4*)(sgp + 4);
      L[2] = *(const f32x4*)(sgp + 32 * DH);
      L[3] = *(const f32x4*)(sgp + 32 * DH + 4);
      stageK(&ldsK[0][0], L, tS);
    } else {
#pragma unroll
      for (int i = 0; i < 4; ++i) L[i] = *(const f32x4*)(sgp + i * DH);
      stageV(&ldsV[0][0], L, tS);
    }
  }
  __syncthreads();

  for (int it = 0; it < nIter; ++it) {
    const int p   = it & 1;
    const int kv0 = it * BK;
    const bool more = (it + 1 < nIter);

    // hoisted LDS bases for this buffer
    const unsigned short* kb = &ldsK[p][(size_t)l15 * KSTR + quad * 8];
    const unsigned short* vb = &ldsV[p][(size_t)l15 * VSTR];

    // ---- phase 1: per-h { kf read, mask load, QK MFMA, exp, pack }
    short4v pf[4];
#pragma unroll
    for (int h = 0; h < 4; ++h) {
      // row l15+16h, cols (quad+4kk)*8 -> base + 1152h + 32kk (shorts, imm)
      const short8 kf0 = *(const short8*)(kb + 1152 * h);
      const short8 kf1 = *(const short8*)(kb + 1152 * h + 32);
      const f32x4 mk = *(const f32x4*)(mrow + kv0 + 16 * h);
      f32x4 c = {0.f, 0.f, 0.f, 0.f};
      __builtin_amdgcn_s_setprio(1);
      c = __builtin_amdgcn_mfma_f32_16x16x32_bf16(kf0, qf0, c, 0, 0, 0);
      c = __builtin_amdgcn_mfma_f32_16x16x32_bf16(kf1, qf1, c, 0, 0, 0);
      __builtin_amdgcn_s_setprio(0);
      float e[4];
#pragma unroll
      for (int r = 0; r < 4; ++r)
        e[r] = __builtin_amdgcn_exp2f(fmaf(mk[r], LOG2E, c[r]));
      union { uint2v u; short4v s; } ue;
      ue.u[0] = packrne(e[0], e[1]);
      ue.u[1] = packrne(e[2], e[3]);
      pf[h] = ue.s;
    }

    // ---- issue next-tile global loads (covered by ls+PV MFMAs below)
    f32x4 L[4];
    if (more) {
      const float* np = sgp + (size_t)(kv0 + BK) * DH;
      if (isK) {
        L[0] = *(const f32x4*)(np);
        L[1] = *(const f32x4*)(np + 4);
        L[2] = *(const f32x4*)(np + 32 * DH);
        L[3] = *(const f32x4*)(np + 32 * DH + 4);
      } else {
#pragma unroll
        for (int i = 0; i < 4; ++i) L[i] = *(const f32x4*)(np + i * DH);
      }
    }

    __builtin_amdgcn_s_setprio(1);
    // row sums on the matrix pipe
#pragma unroll
    for (int h = 0; h < 4; ++h) ls = mfma16(onesf, pf[h], ls);

    // PV: O^T += V^T·P^T
    // vf addr = vb + 1088*nt (imm) + s4[(h+nt)&3] (reg) ; shorts
#pragma unroll
    for (int nt = 0; nt < 4; ++nt) {
#pragma unroll
      for (int h = 0; h < 4; ++h) {
        short4v vf =
            *(const short4v*)(vb + 1088 * nt + s4[(h + nt) & 3]);
        acc[nt] = mfma16(vf, pf[h], acc[nt]);
      }
    }
    __builtin_amdgcn_s_setprio(0);

    // ---- write-late: pack + ds_write the prefetched tile (role-split)
    if (more) {
      if (isK) stageK(&ldsK[p ^ 1][0], L, tS);
      else     stageV(&ldsV[p ^ 1][0], L, tS);
    }
    __syncthreads();
  }

  // ---- epilogue
  if (Lb) {
    // partial: unnormalized acc + l to workspace (combine normalizes)
    const size_t NSV = (size_t)N_B * S_Q * DH;
    float* ob = Ob + (size_t)z * NSV + ((size_t)n * S_Q + (size_t)qrow) * DH
              + quad * 4;
#pragma unroll
    for (int nt = 0; nt < 4; ++nt) *(f32x4*)(ob + 16 * nt) = acc[nt];
    if (quad == 0) {
      float* lp = Lb + (size_t)z * ((size_t)N_B * S_Q) + (size_t)n * S_Q
                + (size_t)qrow;
      lp[0] = ls[0];
    }
  } else {
    // single-pass finalize: O[q][v] = O^T[v][q] / l
    const float inv = 1.0f / ls[0];
    float* ob = Ob + ((size_t)n * S_Q + (size_t)qrow) * DH + quad * 4;
#pragma unroll
    for (int nt = 0; nt < 4; ++nt) {
      f32x4 o;
#pragma unroll
      for (int r = 0; r < 4; ++r) o[r] = acc[nt][r] * inv;
      *(f32x4*)(ob + 16 * nt) = o;
    }
  }
}

// combine: O = (acc0 + acc1) / (l0 + l1); pure streaming, ~85 MB -> ~14 us
__global__ __launch_bounds__(256)
void sdpa_combine(const float* __restrict__ ws, float* __restrict__ Og) {
  constexpr size_t NSV = (size_t)N_B * S_Q * DH;
  constexpr size_t NS  = (size_t)N_B * S_Q;
  const size_t i = (size_t)blockIdx.x * 256 + threadIdx.x;  // f32x4 index
  const f32x4* A0 = (const f32x4*)ws;
  const f32x4* A1 = A0 + NSV / 4;
  const float* L0 = ws + 2 * NSV;
  const float* L1 = L0 + NS;
  const size_t qi = i >> 4;                                 // DH/4 = 16 per row
  const f32x4 a = A0[i], b = A1[i];
  const float inv = 1.0f / (L0[qi] + L1[qi]);
  f32x4 o;
#pragma unroll
  for (int r = 0; r < 4; ++r) o[r] = (a[r] + b[r]) * inv;
  ((f32x4*)Og)[i] = o;
}

extern "C" void kernel_launch(void* const* d_in, const int* in_sizes, int n_in,
                              void* d_out, int out_size, void* d_ws, size_t ws_size,
                              hipStream_t stream) {
  (void)in_sizes; (void)n_in; (void)out_size;
  const float* q = (const float*)d_in[0];
  const float* k = (const float*)d_in[1];
  const float* v = (const float*)d_in[2];
  const float* m = (const float*)d_in[3];
  float* o = (float*)d_out;

  constexpr size_t NSV = (size_t)N_B * S_Q * DH;
  constexpr size_t NS  = (size_t)N_B * S_Q;
  constexpr size_t WS_NEED = (2 * NSV + 2 * NS) * sizeof(float);  // ~34.1 MB

  if (d_ws != nullptr && ws_size >= WS_NEED) {
    float* ws = (float*)d_ws;
    dim3 grid(S_Q / BQ, N_B, 2);   // 1024 blocks x 512 thr -> 4 blocks/CU
    hipLaunchKernelGGL(sdpa_fwd, grid, dim3(512), 0, stream,
                       q, k, v, m, ws, ws + 2 * NSV, ITERS / 2);
    hipLaunchKernelGGL(sdpa_combine, dim3((unsigned)(NSV / 4 / 256)), dim3(256),
                       0, stream, (const float*)ws, o);
  } else {
    // fallback: single-pass, full KV per block (v10 behavior)
    dim3 grid(S_Q / BQ, N_B, 1);
    hipLaunchKernelGGL(sdpa_fwd, grid, dim3(512), 0, stream,
                       q, k, v, m, o, (float*)nullptr, ITERS);
  }
}

// Round 7
// 478.230 us; speedup vs baseline: 1.5441x; 1.5441x over previous
//
#include <hip/hip_runtime.h>
#include <cstdint>
#include <cstddef>

// ---------------------------------------------------------------------------
// NaiveSDPA: out[n,s,v] = softmax(Q·K^T / 8 + mask) · V ; f32 I/O, bf16 MFMA.
// v12: attack the barrier-synced critical path, not occupancy.
// Evidence r0-r6: (a) forcing a reg tier the ~70-reg working set doesn't fit
// spills GBs (r1/r3/r6 — 3x confirmed); (b) 22%->43% occupancy bought only
// 7% (v6 222us -> v10 207us): the limiter is the per-iteration barrier
// critical path (64 barriers, 2 barrier groups/CU), not wave count.
// So v12 = v10/v11 structure with BK=128:
//   - 32 iterations instead of 64: half the barrier drains, half the
//     mask-stall events, 2x longer MFMA/VALU runs between syncs.
//   - mask batch-issued (8 x f32x4) at phase-1 start; regs phase-disjoint
//     with stage transients (mask dies before stage loads issue).
//   - LDS 71.7KB/block (K 2x18KB, V^T 2x17KB) -> 2 blocks/CU = 143KB <= 160.
//   - V^T slot swizzle generalized to 32 slots (&31); K stager covers rows
//     r, r+32, r+64, r+96; all conflict algebra unchanged in character.
//   - KV-split + combine DELETED (cannot raise residency at the 4-wave
//     tier; only added a pass). Single pass, grid (32,16) = 2 blocks/CU.
//   - launch_bounds(512,4): honest 128-reg budget; peak ~104 -> no spills.
// Kept: 8 waves x 16q, role-split staging, Q pre-scaled by 0.125*log2e,
// hoisted LDS bases + slot table, ones-MFMA row-sum, setprio.
// Tripwire: WRITE_SIZE must stay ~16 MB; GB-scale = spills = revert.
// ---------------------------------------------------------------------------

typedef __attribute__((ext_vector_type(8))) short short8;
typedef __attribute__((ext_vector_type(4))) short short4v;
typedef __attribute__((ext_vector_type(4))) float f32x4;
typedef __attribute__((ext_vector_type(4))) unsigned int uint4v;
typedef __attribute__((ext_vector_type(2))) unsigned int uint2v;

#define DEV __device__ __forceinline__

constexpr int N_B   = 16;
constexpr int S_Q   = 4096;
constexpr int S_KV  = 4096;
constexpr int DH    = 64;
constexpr int BQ    = 128;         // q rows per block (8 waves x 16)
constexpr int BK    = 128;         // kv rows per iteration
constexpr int ITERS = S_KV / BK;   // 32
constexpr int KSTR  = 72;          // shorts/K-row: 144B (skew 4 dwords)
constexpr int VSTR  = 136;         // shorts/V^T-row: 32 slots*4 + 8 pad

#define LOG2E 1.44269504088896340736f
#define QSCALE (0.125f * 1.44269504088896340736f)   // fold /8 and log2e into Q

DEV unsigned short f2bf(float f) {           // RNE f32 -> bf16
  union { float f; unsigned int i; } x; x.f = f;
  unsigned int r = x.i + 0x7FFFu + ((x.i >> 16) & 1u);
  return (unsigned short)(r >> 16);
}

#if __has_builtin(__builtin_amdgcn_cvt_pk_bf16_f32)
typedef __attribute__((ext_vector_type(2))) __bf16 bf16x2v;
DEV unsigned int packrne(float a, float b) {   // bf16(a) lo | bf16(b) hi, RNE
  union { bf16x2v v; unsigned int u; } x;
  x.v = __builtin_amdgcn_cvt_pk_bf16_f32(a, b);
  return x.u;
}
#else
DEV unsigned int packrne(float a, float b) {
  union { float f; unsigned int u; } ua, ub; ua.f = a; ub.f = b;
  unsigned int ra = ua.u + 0x7FFFu + ((ua.u >> 16) & 1u);
  unsigned int rb = ub.u + 0x7FFFu + ((ub.u >> 16) & 1u);
  return __builtin_amdgcn_perm(rb, ra, 0x07060302u);
}
#endif

DEV f32x4 mfma16(short4v a, short4v b, f32x4 c) {
#if __has_builtin(__builtin_amdgcn_mfma_f32_16x16x16bf16_1k)
  return __builtin_amdgcn_mfma_f32_16x16x16bf16_1k(a, b, c, 0, 0, 0);
#elif __has_builtin(__builtin_amdgcn_mfma_f32_16x16x16_bf16)
  return __builtin_amdgcn_mfma_f32_16x16x16_bf16(a, b, c, 0, 0, 0);
#else
  asm volatile("v_mfma_f32_16x16x16_bf16 %0, %1, %2, %0\n\ts_nop 7\n\ts_nop 7"
               : "+v"(c) : "v"(a), "v"(b));
  return c;
#endif
}

// stage K tile, BK=128 (256 stager threads): thread tS owns 16B chunks
// (r0+32i, c) for i=0..3, r0=tS>>3, c=tS&7. L[2i],L[2i+1] = row r0+32i.
DEV void stageK(unsigned short* buf, const f32x4* L, int tS) {
  const int r0 = tS >> 3, c = tS & 7;
#pragma unroll
  for (int i = 0; i < 4; ++i) {
    uint4v d;
    d[0] = packrne(L[2*i][0],   L[2*i][1]);
    d[1] = packrne(L[2*i][2],   L[2*i][3]);
    d[2] = packrne(L[2*i+1][0], L[2*i+1][1]);
    d[3] = packrne(L[2*i+1][2], L[2*i+1][3]);
    *(uint4v*)&buf[(r0 + 32 * i) * KSTR + c * 8] = d;
  }
}

// stage V^T, BK=128 (256 stager threads): thread tS loaded L[4*half+i] =
// V[kv = 64*half + 4g + i][4x..4x+3], g=tS>>4, x=tS&15 (coalesced per
// 16-lane phase). Writes chunk a = g+16*half of vcol=4x+j at slot (a+x)&31.
DEV void stageV(unsigned short* buf, const f32x4* L, int tS) {
  const int g = tS >> 4, x = tS & 15;
#pragma unroll
  for (int half = 0; half < 2; ++half) {
    const int slot = ((g + 16 * half) + x) & 31;
#pragma unroll
    for (int j = 0; j < 4; ++j) {
      uint2v d;
      d[0] = packrne(L[4*half + 0][j], L[4*half + 1][j]);
      d[1] = packrne(L[4*half + 2][j], L[4*half + 3][j]);
      *(uint2v*)&buf[(x * 4 + j) * VSTR + slot * 4] = d;
    }
  }
}

__global__ __launch_bounds__(512, 4)
void sdpa_fwd(const float* __restrict__ Qg,
              const float* __restrict__ Kg,
              const float* __restrict__ Vg,
              const float* __restrict__ Mg,
              float* __restrict__ Og)
{
  __shared__ __align__(16) unsigned short ldsK[2][BK * KSTR];  // 2 x 18432 B
  __shared__ __align__(16) unsigned short ldsV[2][DH * VSTR];  // 2 x 17408 B

  const int n    = blockIdx.y;
  const int q0   = blockIdx.x * BQ;
  const int t    = threadIdx.x;
  const int w    = t >> 6;          // wave 0..7: owns q rows q0+16w..+15
  const int lane = t & 63;
  const int l15  = lane & 15;
  const int quad = lane >> 4;
  const int qrow = q0 + w * 16 + l15;

  // ---- Q B-frags, pre-scaled by 0.125*log2e (softmax scale-invariant)
  short8 qf0, qf1;
  {
    const float* qp = Qg + ((size_t)n * S_Q + (size_t)qrow) * DH + quad * 8;
#pragma unroll
    for (int j = 0; j < 8; ++j) {
      qf0[j] = (short)f2bf(qp[j] * QSCALE);
      qf1[j] = (short)f2bf(qp[32 + j] * QSCALE);
    }
  }

  // ---- staging role: waves 0-3 stage K, waves 4-7 stage V (wave-uniform)
  const bool isK = (w < 4);
  const int  tS  = t & 255;
  const float* sgp =
      isK ? Kg + ((size_t)n * S_KV + (size_t)(tS >> 3)) * DH + (tS & 7) * 8
          : Vg + ((size_t)n * S_KV + (size_t)(tS >> 4) * 4) * DH + (tS & 15) * 4;

  const float* mrow = Mg + (size_t)qrow * S_KV + quad * 4;

  // ---- slot table: PV vf slot = (S0 + 4*((h+nt)&7)) & 31, S0=quad+(l15>>2)
  int s8[8];
  {
    const int S0 = quad + (l15 >> 2);
#pragma unroll
    for (int m = 0; m < 8; ++m) s8[m] = ((S0 + 4 * m) & 31) * 4;
  }

  // ---- O^T accumulators (C-layout: row v=16nt+quad*4+r, col q=l15)
  f32x4 acc[4];
#pragma unroll
  for (int nt = 0; nt < 4; ++nt)
#pragma unroll
    for (int r = 0; r < 4; ++r) acc[nt][r] = 0.0f;

  // ---- l accumulator via ones-MFMA (rows all equal; read [0] at the end)
  f32x4 ls = {0.f, 0.f, 0.f, 0.f};
  const short4v onesf = {(short)0x3F80, (short)0x3F80,
                         (short)0x3F80, (short)0x3F80};  // bf16 1.0

  // ---- prologue: load + stage tile 0 (role-split)
  {
    f32x4 L[8];
    if (isK) {
#pragma unroll
      for (int i = 0; i < 4; ++i) {
        L[2*i]   = *(const f32x4*)(sgp + (size_t)i * 32 * DH);
        L[2*i+1] = *(const f32x4*)(sgp + (size_t)i * 32 * DH + 4);
      }
      stageK(&ldsK[0][0], L, tS);
    } else {
#pragma unroll
      for (int half = 0; half < 2; ++half)
#pragma unroll
        for (int i = 0; i < 4; ++i)
          L[4*half + i] = *(const f32x4*)(sgp + (size_t)(64*half + i) * DH);
      stageV(&ldsV[0][0], L, tS);
    }
  }
  __syncthreads();

  for (int it = 0; it < ITERS; ++it) {
    const int p   = it & 1;
    const int kv0 = it * BK;
    const bool more = (it + 1 < ITERS);

    // hoisted LDS bases for this buffer
    const unsigned short* kb = &ldsK[p][(size_t)l15 * KSTR + quad * 8];
    const unsigned short* vb = &ldsV[p][(size_t)l15 * VSTR];

    // ---- phase 1: batch mask loads, then per-h { kf, QK MFMA, exp, pack }
    f32x4 mk[8];
#pragma unroll
    for (int h = 0; h < 8; ++h)
      mk[h] = *(const f32x4*)(mrow + kv0 + 16 * h);

    short4v pf[8];
#pragma unroll
    for (int h = 0; h < 8; ++h) {
      // row l15+16h, cols (quad+4kk)*8 -> kb + 1152h + 32kk (shorts, imm)
      const short8 kf0 = *(const short8*)(kb + 1152 * h);
      const short8 kf1 = *(const short8*)(kb + 1152 * h + 32);
      f32x4 c = {0.f, 0.f, 0.f, 0.f};
      __builtin_amdgcn_s_setprio(1);
      c = __builtin_amdgcn_mfma_f32_16x16x32_bf16(kf0, qf0, c, 0, 0, 0);
      c = __builtin_amdgcn_mfma_f32_16x16x32_bf16(kf1, qf1, c, 0, 0, 0);
      __builtin_amdgcn_s_setprio(0);
      float e[4];
#pragma unroll
      for (int r = 0; r < 4; ++r)
        e[r] = __builtin_amdgcn_exp2f(fmaf(mk[h][r], LOG2E, c[r]));
      union { uint2v u; short4v s; } ue;
      ue.u[0] = packrne(e[0], e[1]);
      ue.u[1] = packrne(e[2], e[3]);
      pf[h] = ue.s;
    }

    // ---- issue next-tile global loads (covered by ls+PV MFMAs below);
    // mask regs are dead here -> stage transients reuse the budget.
    f32x4 L[8];
    if (more) {
      const float* np = sgp + (size_t)(kv0 + BK) * DH;
      if (isK) {
#pragma unroll
        for (int i = 0; i < 4; ++i) {
          L[2*i]   = *(const f32x4*)(np + (size_t)i * 32 * DH);
          L[2*i+1] = *(const f32x4*)(np + (size_t)i * 32 * DH + 4);
        }
      } else {
#pragma unroll
        for (int half = 0; half < 2; ++half)
#pragma unroll
          for (int i = 0; i < 4; ++i)
            L[4*half + i] = *(const f32x4*)(np + (size_t)(64*half + i) * DH);
      }
    }

    __builtin_amdgcn_s_setprio(1);
    // row sums on the matrix pipe
#pragma unroll
    for (int h = 0; h < 8; ++h) ls = mfma16(onesf, pf[h], ls);

    // PV: O^T += V^T·P^T ; vf addr = vb + 2176*nt (imm) + s8[(h+nt)&7]
#pragma unroll
    for (int nt = 0; nt < 4; ++nt) {
#pragma unroll
      for (int h = 0; h < 8; ++h) {
        short4v vf = *(const short4v*)(vb + 2176 * nt + s8[(h + nt) & 7]);
        acc[nt] = mfma16(vf, pf[h], acc[nt]);
      }
    }
    __builtin_amdgcn_s_setprio(0);

    // ---- write-late: pack + ds_write the prefetched tile (role-split)
    if (more) {
      if (isK) stageK(&ldsK[p ^ 1][0], L, tS);
      else     stageV(&ldsV[p ^ 1][0], L, tS);
    }
    __syncthreads();
  }

  // ---- epilogue: O[q][v] = O^T[v][q] / l ; coalesced f32x4 stores
  const float inv = 1.0f / ls[0];
  float* ob = Og + ((size_t)n * S_Q + (size_t)qrow) * DH + quad * 4;
#pragma unroll
  for (int nt = 0; nt < 4; ++nt) {
    f32x4 o;
#pragma unroll
    for (int r = 0; r < 4; ++r) o[r] = acc[nt][r] * inv;
    *(f32x4*)(ob + 16 * nt) = o;
  }
}

extern "C" void kernel_launch(void* const* d_in, const int* in_sizes, int n_in,
                              void* d_out, int out_size, void* d_ws, size_t ws_size,
                              hipStream_t stream) {
  (void)in_sizes; (void)n_in; (void)d_ws; (void)ws_size; (void)out_size;
  const float* q = (const float*)d_in[0];
  const float* k = (const float*)d_in[1];
  const float* v = (const float*)d_in[2];
  const float* m = (const float*)d_in[3];
  float* o = (float*)d_out;

  dim3 grid(S_Q / BQ, N_B);   // (32, 16) = 512 blocks of 512 thr = 2 blocks/CU
  dim3 block(512);
  hipLaunchKernelGGL(sdpa_fwd, grid, block, 0, stream, q, k, v, m, o);
}

// Round 8
// 307.863 us; speedup vs baseline: 2.3986x; 1.5534x over previous
//
#include <hip/hip_runtime.h>
#include <cstdint>
#include <cstddef>

// ---------------------------------------------------------------------------
// NaiveSDPA: out[n,s,v] = softmax(Q·K^T / 8 + mask) · V ; f32 I/O, bf16 MFMA.
// v13: fit the 64-reg tier honestly; hedge the spill risk at runtime.
// Ledger from r0-r7 (4 spill events): occupancy tiers are power-of-2 on
// COMBINED arch+acc regs; CSV VGPR_Count excludes acc. v10 = 48 arch +
// 20 acc (acc 16 + ls 4) = 68 -> 128-tier -> 2 blocks/CU. BK=128 (r7) and
// forced bounds (r1/r3/r6) all spilled GBs. v13 closes the 68->64 gap
// structurally:
//   - DROP ones-MFMA row-sum (ls 4 acc + onesf 2): per-thread scalar
//     rs += sum(e) each iter; ONE shfl_xor(16)+shfl_xor(32) in the
//     epilogue (per-iter cross-lane reduce was never needed). ~62 combined.
//   - launch_bounds(512,8) on the primary build -> 8 waves/SIMD tier;
//     KV-split x2 grid (32,16,2)=1024 blocks -> 4 blocks/CU = 32 waves/CU
//     (LDS 4x35.8KB=143KB<=160, threads 2048<=2048).
//   - RUNTIME SPILL TRIPWIRE: hipFuncGetAttributes(localSizeBytes) on the
//     (512,8) build at first launch (host query, capture-safe). If the
//     compiler spilled, fall back to the (512,4) single-pass build
//     (v10-equivalent codegen) -> worst case ~= current best, never a
//     2-3x spill regression again.
// Kept from v10: 8 waves x 16q, role-split K/V staging, BK=64 double
// buffer, swizzled V^T (16 slots), skewed K rows, setprio, write-late
// staging, Q pre-scaled by 0.125*log2e (exp arg = fmaf(mk,log2e,c)).
// ---------------------------------------------------------------------------

typedef __attribute__((ext_vector_type(8))) short short8;
typedef __attribute__((ext_vector_type(4))) short short4v;
typedef __attribute__((ext_vector_type(4))) float f32x4;
typedef __attribute__((ext_vector_type(4))) unsigned int uint4v;
typedef __attribute__((ext_vector_type(2))) unsigned int uint2v;

#define DEV __device__ __forceinline__

constexpr int N_B   = 16;
constexpr int S_Q   = 4096;
constexpr int S_KV  = 4096;
constexpr int DH    = 64;
constexpr int BQ    = 128;         // q rows per block (8 waves x 16)
constexpr int BK    = 64;
constexpr int ITERS = S_KV / BK;   // 64
constexpr int KSTR  = 72;          // shorts/row: 144B (skew 4 dwords)
constexpr int VSTR  = 68;          // shorts/row: 136B (16 slots + 4 pad)

#define LOG2E 1.44269504088896340736f
#define QSCALE (0.125f * 1.44269504088896340736f)   // fold /8 + log2e into Q

DEV unsigned short f2bf(float f) {           // RNE f32 -> bf16
  union { float f; unsigned int i; } x; x.f = f;
  unsigned int r = x.i + 0x7FFFu + ((x.i >> 16) & 1u);
  return (unsigned short)(r >> 16);
}

#if __has_builtin(__builtin_amdgcn_cvt_pk_bf16_f32)
typedef __attribute__((ext_vector_type(2))) __bf16 bf16x2v;
DEV unsigned int packrne(float a, float b) {   // bf16(a) lo | bf16(b) hi, RNE
  union { bf16x2v v; unsigned int u; } x;
  x.v = __builtin_amdgcn_cvt_pk_bf16_f32(a, b);
  return x.u;
}
#else
DEV unsigned int packrne(float a, float b) {
  union { float f; unsigned int u; } ua, ub; ua.f = a; ub.f = b;
  unsigned int ra = ua.u + 0x7FFFu + ((ua.u >> 16) & 1u);
  unsigned int rb = ub.u + 0x7FFFu + ((ub.u >> 16) & 1u);
  return __builtin_amdgcn_perm(rb, ra, 0x07060302u);
}
#endif

DEV f32x4 mfma16(short4v a, short4v b, f32x4 c) {
#if __has_builtin(__builtin_amdgcn_mfma_f32_16x16x16bf16_1k)
  return __builtin_amdgcn_mfma_f32_16x16x16bf16_1k(a, b, c, 0, 0, 0);
#elif __has_builtin(__builtin_amdgcn_mfma_f32_16x16x16_bf16)
  return __builtin_amdgcn_mfma_f32_16x16x16_bf16(a, b, c, 0, 0, 0);
#else
  asm volatile("v_mfma_f32_16x16x16_bf16 %0, %1, %2, %0\n\ts_nop 7\n\ts_nop 7"
               : "+v"(c) : "v"(a), "v"(b));
  return c;
#endif
}

// stage K tile (256 stager threads): thread tS owns 16B chunks
// (r=tS>>3, c=tS&7) and (r+32, c). L = {row r: lo,hi ; row r+32: lo,hi}.
DEV void stageK(unsigned short* buf, const f32x4* L, int tS) {
  const int r0 = tS >> 3, c = tS & 7;
  uint4v d0, d1;
  d0[0] = packrne(L[0][0], L[0][1]); d0[1] = packrne(L[0][2], L[0][3]);
  d0[2] = packrne(L[1][0], L[1][1]); d0[3] = packrne(L[1][2], L[1][3]);
  d1[0] = packrne(L[2][0], L[2][1]); d1[1] = packrne(L[2][2], L[2][3]);
  d1[2] = packrne(L[3][0], L[3][1]); d1[3] = packrne(L[3][2], L[3][3]);
  *(uint4v*)&buf[r0 * KSTR + c * 8]        = d0;
  *(uint4v*)&buf[(r0 + 32) * KSTR + c * 8] = d1;
}

// stage V^T (256 stager threads): thread tS loaded L[i] =
// V[kv=4*(tS>>4)+i][4*(tS&15)..+3] (coalesced per 16-lane phase). Writes
// chunk a=tS>>4 of vcol=4x+j (x=tS&15) at slot (a+x)&15: conflict-free.
DEV void stageV(unsigned short* buf, const f32x4* L, int tS) {
  const int a = tS >> 4;          // kv-chunk
  const int x = tS & 15;          // vcol>>2
  const int slot = (a + x) & 15;
#pragma unroll
  for (int j = 0; j < 4; ++j) {
    uint2v d;
    d[0] = packrne(L[0][j], L[1][j]);
    d[1] = packrne(L[2][j], L[3][j]);
    *(uint2v*)&buf[(x * 4 + j) * VSTR + slot * 4] = d;
  }
}

template <int MW>
__global__ __launch_bounds__(512, MW)
void sdpa_fwd(const float* __restrict__ Qg,
              const float* __restrict__ Kg,
              const float* __restrict__ Vg,
              const float* __restrict__ Mg,
              float* __restrict__ Ob,    // Og (finalize) or ws acc base
              float* __restrict__ Lb,    // nullptr (finalize) or ws l base
              int nIter)
{
  __shared__ __align__(16) unsigned short ldsK[2][BK * KSTR];  // 2 x 9216 B
  __shared__ __align__(16) unsigned short ldsV[2][DH * VSTR];  // 2 x 8704 B

  const int n    = blockIdx.y;
  const int q0   = blockIdx.x * BQ;
  const int z    = blockIdx.z;                   // kv slice
  const size_t kvbase = (size_t)z * (size_t)nIter * BK;  // SGPR-only math
  const int t    = threadIdx.x;
  const int w    = t >> 6;          // wave 0..7: owns q rows q0+16w..+15
  const int lane = t & 63;
  const int l15  = lane & 15;
  const int quad = lane >> 4;
  const int qrow = q0 + w * 16 + l15;

  // ---- Q B-frags, pre-scaled by 0.125*log2e (softmax scale-invariant)
  short8 qf0, qf1;
  {
    const float* qp = Qg + ((size_t)n * S_Q + (size_t)qrow) * DH + quad * 8;
#pragma unroll
    for (int j = 0; j < 8; ++j) {
      qf0[j] = (short)f2bf(qp[j] * QSCALE);
      qf1[j] = (short)f2bf(qp[32 + j] * QSCALE);
    }
  }

  // ---- staging role: waves 0-3 stage K, waves 4-7 stage V (wave-uniform)
  const bool isK = (w < 4);
  const int  tS  = t & 255;
  const float* sgp =
      isK ? Kg + ((size_t)n * S_KV + kvbase + (size_t)(tS >> 3)) * DH
              + (tS & 7) * 8
          : Vg + ((size_t)n * S_KV + kvbase + (size_t)(tS >> 4) * 4) * DH
              + (tS & 15) * 4;

  const float* mrow = Mg + (size_t)qrow * S_KV + kvbase + quad * 4;

  // ---- O^T accumulators (C-layout: row v=16nt+quad*4+r, col q=l15)
  f32x4 acc[4];
#pragma unroll
  for (int nt = 0; nt < 4; ++nt)
#pragma unroll
    for (int r = 0; r < 4; ++r) acc[nt][r] = 0.0f;

  // ---- per-thread partial row-sum (cross-quad reduce ONCE in epilogue)
  float rs = 0.0f;

  // ---- prologue: load + stage tile 0 (role-split)
  {
    f32x4 L[4];
    if (isK) {
      L[0] = *(const f32x4*)(sgp);
      L[1] = *(const f32x4*)(sgp + 4);
      L[2] = *(const f32x4*)(sgp + 32 * DH);
      L[3] = *(const f32x4*)(sgp + 32 * DH + 4);
      stageK(&ldsK[0][0], L, tS);
    } else {
#pragma unroll
      for (int i = 0; i < 4; ++i) L[i] = *(const f32x4*)(sgp + i * DH);
      stageV(&ldsV[0][0], L, tS);
    }
  }
  __syncthreads();

  for (int it = 0; it < nIter; ++it) {
    const int p   = it & 1;
    const int kv0 = it * BK;
    const bool more = (it + 1 < nIter);

    // ---- phase 1: per-h { kf read, mask load, QK MFMA, exp, rs, pack }
    short4v pf[4];
#pragma unroll
    for (int h = 0; h < 4; ++h) {
      const short8 kf0 =
          *(const short8*)&ldsK[p][(l15 + 16 * h) * KSTR + quad * 8];
      const short8 kf1 =
          *(const short8*)&ldsK[p][(l15 + 16 * h) * KSTR + (quad + 4) * 8];
      const f32x4 mk = *(const f32x4*)(mrow + kv0 + 16 * h);
      f32x4 c = {0.f, 0.f, 0.f, 0.f};
      __builtin_amdgcn_s_setprio(1);
      c = __builtin_amdgcn_mfma_f32_16x16x32_bf16(kf0, qf0, c, 0, 0, 0);
      c = __builtin_amdgcn_mfma_f32_16x16x32_bf16(kf1, qf1, c, 0, 0, 0);
      __builtin_amdgcn_s_setprio(0);
      float e[4];
#pragma unroll
      for (int r = 0; r < 4; ++r)
        e[r] = __builtin_amdgcn_exp2f(fmaf(mk[r], LOG2E, c[r]));
      rs += (e[0] + e[1]) + (e[2] + e[3]);
      union { uint2v u; short4v s; } ue;
      ue.u[0] = packrne(e[0], e[1]);
      ue.u[1] = packrne(e[2], e[3]);
      pf[h] = ue.s;
    }

    // ---- issue next-tile global loads (covered by PV MFMAs below)
    f32x4 L[4];
    if (more) {
      const float* np = sgp + (size_t)(kv0 + BK) * DH;
      if (isK) {
        L[0] = *(const f32x4*)(np);
        L[1] = *(const f32x4*)(np + 4);
        L[2] = *(const f32x4*)(np + 32 * DH);
        L[3] = *(const f32x4*)(np + 32 * DH + 4);
      } else {
#pragma unroll
        for (int i = 0; i < 4; ++i) L[i] = *(const f32x4*)(np + i * DH);
      }
    }

    // PV: O^T += V^T·P^T
    // vf = V^T[vcol=l15+16nt][kv chunk c=4h+quad] at slot (c + vcol/4)&15
    __builtin_amdgcn_s_setprio(1);
#pragma unroll
    for (int nt = 0; nt < 4; ++nt) {
      const int vcol = l15 + 16 * nt;
      const int xr   = (l15 >> 2) + 4 * nt;
#pragma unroll
      for (int h = 0; h < 4; ++h) {
        const int slot = ((4 * h + quad) + xr) & 15;
        short4v vf = *(const short4v*)&ldsV[p][vcol * VSTR + slot * 4];
        acc[nt] = mfma16(vf, pf[h], acc[nt]);
      }
    }
    __builtin_amdgcn_s_setprio(0);

    // ---- write-late: pack + ds_write the prefetched tile (role-split)
    if (more) {
      if (isK) stageK(&ldsK[p ^ 1][0], L, tS);
      else     stageV(&ldsV[p ^ 1][0], L, tS);
    }
    __syncthreads();
  }

  // ---- epilogue: single cross-quad reduce for the row sum
  rs += __shfl_xor(rs, 16, 64);
  rs += __shfl_xor(rs, 32, 64);

  if (Lb) {
    // partial: unnormalized acc + l to workspace (combine normalizes)
    const size_t NSV = (size_t)N_B * S_Q * DH;
    float* ob = Ob + (size_t)z * NSV + ((size_t)n * S_Q + (size_t)qrow) * DH
              + quad * 4;
#pragma unroll
    for (int nt = 0; nt < 4; ++nt) *(f32x4*)(ob + 16 * nt) = acc[nt];
    if (quad == 0) {
      float* lp = Lb + (size_t)z * ((size_t)N_B * S_Q) + (size_t)n * S_Q
                + (size_t)qrow;
      lp[0] = rs;
    }
  } else {
    // single-pass finalize: O[q][v] = O^T[v][q] / l
    const float inv = 1.0f / rs;
    float* ob = Ob + ((size_t)n * S_Q + (size_t)qrow) * DH + quad * 4;
#pragma unroll
    for (int nt = 0; nt < 4; ++nt) {
      f32x4 o;
#pragma unroll
      for (int r = 0; r < 4; ++r) o[r] = acc[nt][r] * inv;
      *(f32x4*)(ob + 16 * nt) = o;
    }
  }
}

// combine: O = (acc0 + acc1) / (l0 + l1); pure streaming, ~50 MB -> ~10 us
__global__ __launch_bounds__(256)
void sdpa_combine(const float* __restrict__ ws, float* __restrict__ Og) {
  constexpr size_t NSV = (size_t)N_B * S_Q * DH;
  constexpr size_t NS  = (size_t)N_B * S_Q;
  const size_t i = (size_t)blockIdx.x * 256 + threadIdx.x;  // f32x4 index
  const f32x4* A0 = (const f32x4*)ws;
  const f32x4* A1 = A0 + NSV / 4;
  const float* L0 = ws + 2 * NSV;
  const float* L1 = L0 + NS;
  const size_t qi = i >> 4;                                 // DH/4 = 16 per row
  const f32x4 a = A0[i], b = A1[i];
  const float inv = 1.0f / (L0[qi] + L1[qi]);
  f32x4 o;
#pragma unroll
  for (int r = 0; r < 4; ++r) o[r] = (a[r] + b[r]) * inv;
  ((f32x4*)Og)[i] = o;
}

extern "C" void kernel_launch(void* const* d_in, const int* in_sizes, int n_in,
                              void* d_out, int out_size, void* d_ws, size_t ws_size,
                              hipStream_t stream) {
  (void)in_sizes; (void)n_in; (void)out_size;
  const float* q = (const float*)d_in[0];
  const float* k = (const float*)d_in[1];
  const float* v = (const float*)d_in[2];
  const float* m = (const float*)d_in[3];
  float* o = (float*)d_out;

  constexpr size_t NSV = (size_t)N_B * S_Q * DH;
  constexpr size_t NS  = (size_t)N_B * S_Q;
  constexpr size_t WS_NEED = (2 * NSV + 2 * NS) * sizeof(float);  // ~34.1 MB

  // Spill tripwire: use the (512,8) build only if the compiler delivered it
  // with ZERO scratch. Host-side attribute query — graph-capture safe.
  static int use8 = -1;
  if (use8 < 0) {
    hipFuncAttributes attr{};
    use8 = 0;
    if (hipFuncGetAttributes(&attr,
            reinterpret_cast<const void*>(&sdpa_fwd<8>)) == hipSuccess &&
        attr.localSizeBytes == 0)
      use8 = 1;
  }

  if (use8 && d_ws != nullptr && ws_size >= WS_NEED) {
    float* ws = (float*)d_ws;
    dim3 grid(S_Q / BQ, N_B, 2);   // 1024 blocks x 512 thr -> 4 blocks/CU
    hipLaunchKernelGGL(sdpa_fwd<8>, grid, dim3(512), 0, stream,
                       q, k, v, m, ws, ws + 2 * NSV, ITERS / 2);
    hipLaunchKernelGGL(sdpa_combine, dim3((unsigned)(NSV / 4 / 256)), dim3(256),
                       0, stream, (const float*)ws, o);
  } else {
    // fallback: proven no-spill (512,4) single-pass (v10-equivalent)
    dim3 grid(S_Q / BQ, N_B, 1);
    hipLaunchKernelGGL(sdpa_fwd<4>, grid, dim3(512), 0, stream,
                       q, k, v, m, o, (float*)nullptr, ITERS);
  }
}

// Round 9
// 295.709 us; speedup vs baseline: 2.4972x; 1.0411x over previous
//
#include <hip/hip_runtime.h>
#include <cstdint>
#include <cstddef>

// ---------------------------------------------------------------------------
// NaiveSDPA: out[n,s,v] = softmax(Q·K^T / 8 + mask) · V ; f32 I/O, bf16 MFMA.
// v14: hoist K/V bf16 conversion OUT of the loop; DMA-stage pre-baked tiles.
// Evidence r0-r8: (a) 5x confirmed: the ~68-reg working set can't be dieted
// below 64 at source level; (b) VALUBusy 40% is the top pipe and ~half of it
// is the f32->bf16 staging pack (cvt_pk_bf16_f32 has NO builtin on gfx950,
// so each pack is a ~7-op bit-twiddle), re-converting every K/V tile 32x.
// v14:
//   - sdpa_prep (~6us): converts K/V once into pre-swizzled bf16 LDS-tile
//     IMAGES in workspace — byte-identical to the ldsK (144B skewed rows)
//     and ldsV (slot-swizzled V^T) layouts. 18432B/tile, 18.9MB total.
//   - main loop stages via __builtin_amdgcn_global_load_lds width=16
//     (9 wave-rounds per tile): zero staging VALU, zero staging regs, no
//     ds_writes, no write-late phase. Images are L3-resident.
//   - working set drops to ~55 combined regs -> honest shot at the 64-tier:
//     primary = launch_bounds(512,8) + KV-split x2 (4 blocks/CU; LDS
//     4x36KB=144KB<=160); tripwire (r8-proven hipFuncGetAttributes) falls
//     back to (512,4) single-pass DMA; ultimate fallback = v13 reg-staging.
// Compute/layout/numerics byte-identical to r8-verified kernel.
// ---------------------------------------------------------------------------

typedef __attribute__((ext_vector_type(8))) short short8;
typedef __attribute__((ext_vector_type(4))) short short4v;
typedef __attribute__((ext_vector_type(4))) float f32x4;
typedef __attribute__((ext_vector_type(4))) unsigned int uint4v;
typedef __attribute__((ext_vector_type(2))) unsigned int uint2v;

#define DEV __device__ __forceinline__

constexpr int N_B   = 16;
constexpr int S_Q   = 4096;
constexpr int S_KV  = 4096;
constexpr int DH    = 64;
constexpr int BQ    = 128;         // q rows per block (8 waves x 16)
constexpr int BK    = 64;
constexpr int ITERS = S_KV / BK;   // 64 tiles
constexpr int KSTR  = 72;          // shorts/K-row: 144B (skew 4 dwords)
constexpr int VSTR  = 68;          // shorts/V^T-row: 136B (16 slots + pad)
constexpr int KIMG_B = 9216;       // K tile image bytes  (576 x 16B chunks)
constexpr int VIMG_B = 9216;       // V tile image bytes  (8704 + 512 pad)
constexpr int TILE_B = KIMG_B + VIMG_B;   // 18432

#define LOG2E 1.44269504088896340736f
#define QSCALE (0.125f * 1.44269504088896340736f)   // fold /8 + log2e into Q

DEV unsigned short f2bf(float f) {           // RNE f32 -> bf16
  union { float f; unsigned int i; } x; x.f = f;
  unsigned int r = x.i + 0x7FFFu + ((x.i >> 16) & 1u);
  return (unsigned short)(r >> 16);
}

#if __has_builtin(__builtin_amdgcn_cvt_pk_bf16_f32)
typedef __attribute__((ext_vector_type(2))) __bf16 bf16x2v;
DEV unsigned int packrne(float a, float b) {   // bf16(a) lo | bf16(b) hi, RNE
  union { bf16x2v v; unsigned int u; } x;
  x.v = __builtin_amdgcn_cvt_pk_bf16_f32(a, b);
  return x.u;
}
#else
DEV unsigned int packrne(float a, float b) {
  union { float f; unsigned int u; } ua, ub; ua.f = a; ub.f = b;
  unsigned int ra = ua.u + 0x7FFFu + ((ua.u >> 16) & 1u);
  unsigned int rb = ub.u + 0x7FFFu + ((ub.u >> 16) & 1u);
  return __builtin_amdgcn_perm(rb, ra, 0x07060302u);
}
#endif

DEV f32x4 mfma16(short4v a, short4v b, f32x4 c) {
#if __has_builtin(__builtin_amdgcn_mfma_f32_16x16x16bf16_1k)
  return __builtin_amdgcn_mfma_f32_16x16x16bf16_1k(a, b, c, 0, 0, 0);
#elif __has_builtin(__builtin_amdgcn_mfma_f32_16x16x16_bf16)
  return __builtin_amdgcn_mfma_f32_16x16x16_bf16(a, b, c, 0, 0, 0);
#else
  asm volatile("v_mfma_f32_16x16x16_bf16 %0, %1, %2, %0\n\ts_nop 7\n\ts_nop 7"
               : "+v"(c) : "v"(a), "v"(b));
  return c;
#endif
}

// stage K tile image (256 threads): thread tS owns 16B chunks
// (r=tS>>3, c=tS&7) and (r+32, c). Row r chunk c = bf16 K[r][8c..8c+7].
DEV void stageK(unsigned short* buf, const f32x4* L, int tS) {
  const int r0 = tS >> 3, c = tS & 7;
  uint4v d0, d1;
  d0[0] = packrne(L[0][0], L[0][1]); d0[1] = packrne(L[0][2], L[0][3]);
  d0[2] = packrne(L[1][0], L[1][1]); d0[3] = packrne(L[1][2], L[1][3]);
  d1[0] = packrne(L[2][0], L[2][1]); d1[1] = packrne(L[2][2], L[2][3]);
  d1[2] = packrne(L[3][0], L[3][1]); d1[3] = packrne(L[3][2], L[3][3]);
  *(uint4v*)&buf[r0 * KSTR + c * 8]        = d0;
  *(uint4v*)&buf[(r0 + 32) * KSTR + c * 8] = d1;
}

// stage V^T tile image (256 threads): thread tS loaded L[i] =
// V[kv=4*(tS>>4)+i][4*(tS&15)..+3]. Writes chunk a=tS>>4 of vcol=4x+j
// (x=tS&15) at slot (a+x)&15 on 136B rows: conflict-free pattern.
DEV void stageV(unsigned short* buf, const f32x4* L, int tS) {
  const int a = tS >> 4;          // kv-chunk
  const int x = tS & 15;          // vcol>>2
  const int slot = (a + x) & 15;
#pragma unroll
  for (int j = 0; j < 4; ++j) {
    uint2v d;
    d[0] = packrne(L[0][j], L[1][j]);
    d[1] = packrne(L[2][j], L[3][j]);
    *(uint2v*)&buf[(x * 4 + j) * VSTR + slot * 4] = d;
  }
}

// async 16B global->LDS DMA: LDS dest = wave-uniform base + lane*16 (HW),
// global src = per-lane address.
DEV void dma16(const void* g, void* l) {
#if __has_builtin(__builtin_amdgcn_global_load_lds)
  __builtin_amdgcn_global_load_lds(
      (const __attribute__((address_space(1))) unsigned int*)g,
      (__attribute__((address_space(3))) unsigned int*)l, 16, 0, 0);
#else
  ((uint4v*)l)[threadIdx.x & 63] = *(const uint4v*)g;   // sync fallback
#endif
}

// DMA one tile image into LDS: K image = 576 chunks (waves 0-3 x2 + wave0
// x1), V image = 576 chunks incl pad (waves 4-7 x2 + wave4 x1). All bases
// wave-uniform; 9 wave-rounds total, no predication.
DEV void dmaTile(const char* gt, void* lk, void* lv, int w, int laneB) {
  if (w < 4) {
    const int base = w * 2048;
    dma16(gt + base + laneB,        (char*)lk + base);
    dma16(gt + base + 1024 + laneB, (char*)lk + base + 1024);
    if (w == 0) dma16(gt + 8192 + laneB, (char*)lk + 8192);
  } else {
    const char* g = gt + KIMG_B;
    const int base = (w - 4) * 2048;
    dma16(g + base + laneB,        (char*)lv + base);
    dma16(g + base + 1024 + laneB, (char*)lv + base + 1024);
    if (w == 4) dma16(g + 8192 + laneB, (char*)lv + 8192);
  }
}

// ---- prep: build per-(n,tile) bf16 LDS images in workspace (runs ~6us)
__global__ __launch_bounds__(256)
void sdpa_prep(const float* __restrict__ Kg, const float* __restrict__ Vg,
               unsigned short* __restrict__ imgs) {
  const int b   = blockIdx.x;           // n*64 + tau
  const int n   = b >> 6, tau = b & 63;
  const int tS  = threadIdx.x;
  unsigned short* img = imgs + (size_t)b * (TILE_B / 2);
  {
    const float* kp =
        Kg + ((size_t)n * S_KV + tau * 64 + (tS >> 3)) * DH + (tS & 7) * 8;
    f32x4 L[4];
    L[0] = *(const f32x4*)(kp);
    L[1] = *(const f32x4*)(kp + 4);
    L[2] = *(const f32x4*)(kp + 32 * DH);
    L[3] = *(const f32x4*)(kp + 32 * DH + 4);
    stageK(img, L, tS);
  }
  {
    const float* vp =
        Vg + ((size_t)n * S_KV + tau * 64 + (size_t)(tS >> 4) * 4) * DH
           + (tS & 15) * 4;
    f32x4 L[4];
#pragma unroll
    for (int i = 0; i < 4; ++i) L[i] = *(const f32x4*)(vp + i * DH);
    stageV(img + KIMG_B / 2, L, tS);
  }
}

// ---- main: DMA-staged attention
template <int MW>
__global__ __launch_bounds__(512, MW)
void sdpa_fwd_dma(const float* __restrict__ Qg,
                  const float* __restrict__ Mg,
                  const unsigned short* __restrict__ imgs,
                  float* __restrict__ Ob,   // Og (finalize) or ws acc base
                  float* __restrict__ Lb,   // nullptr (finalize) or ws l base
                  int nIter)
{
  __shared__ __align__(16) unsigned short ldsK[2][KIMG_B / 2];
  __shared__ __align__(16) unsigned short ldsV[2][VIMG_B / 2];

  const int n     = blockIdx.y;
  const int q0    = blockIdx.x * BQ;
  const int z     = blockIdx.z;                 // kv slice
  const int t     = threadIdx.x;
  const int w     = t >> 6;                     // wave 0..7
  const int lane  = t & 63;
  const int l15   = lane & 15;
  const int quad  = lane >> 4;
  const int qrow  = q0 + w * 16 + l15;
  const int laneB = lane * 16;
  const int tbase = n * 64 + z * nIter;         // first tile of this block

  // Q B-frags, pre-scaled by 0.125*log2e (softmax scale-invariant)
  short8 qf0, qf1;
  {
    const float* qp = Qg + ((size_t)n * S_Q + (size_t)qrow) * DH + quad * 8;
#pragma unroll
    for (int j = 0; j < 8; ++j) {
      qf0[j] = (short)f2bf(qp[j] * QSCALE);
      qf1[j] = (short)f2bf(qp[32 + j] * QSCALE);
    }
  }

  const float* mrow =
      Mg + (size_t)qrow * S_KV + (size_t)z * nIter * BK + quad * 4;

  f32x4 acc[4];
#pragma unroll
  for (int nt = 0; nt < 4; ++nt)
#pragma unroll
    for (int r = 0; r < 4; ++r) acc[nt][r] = 0.0f;
  float rs = 0.0f;                 // per-thread partial row sum

  // prologue: DMA tile 0
  dmaTile((const char*)imgs + (size_t)tbase * TILE_B,
          &ldsK[0][0], &ldsV[0][0], w, laneB);
  __syncthreads();

  for (int it = 0; it < nIter; ++it) {
    const int p   = it & 1;
    const int kv0 = it * BK;
    const bool more = (it + 1 < nIter);

    // issue next-tile DMA first: covered by the whole compute phase
    if (more)
      dmaTile((const char*)imgs + (size_t)(tbase + it + 1) * TILE_B,
              &ldsK[p ^ 1][0], &ldsV[p ^ 1][0], w, laneB);

    // phase 1: per-h { kf read, mask load, QK MFMA, exp, rs, pack }
    short4v pf[4];
#pragma unroll
    for (int h = 0; h < 4; ++h) {
      const short8 kf0 =
          *(const short8*)&ldsK[p][(l15 + 16 * h) * KSTR + quad * 8];
      const short8 kf1 =
          *(const short8*)&ldsK[p][(l15 + 16 * h) * KSTR + (quad + 4) * 8];
      const f32x4 mk = *(const f32x4*)(mrow + kv0 + 16 * h);
      f32x4 c = {0.f, 0.f, 0.f, 0.f};
      __builtin_amdgcn_s_setprio(1);
      c = __builtin_amdgcn_mfma_f32_16x16x32_bf16(kf0, qf0, c, 0, 0, 0);
      c = __builtin_amdgcn_mfma_f32_16x16x32_bf16(kf1, qf1, c, 0, 0, 0);
      __builtin_amdgcn_s_setprio(0);
      float e[4];
#pragma unroll
      for (int r = 0; r < 4; ++r)
        e[r] = __builtin_amdgcn_exp2f(fmaf(mk[r], LOG2E, c[r]));
      rs += (e[0] + e[1]) + (e[2] + e[3]);
      union { uint2v u; short4v s; } ue;
      ue.u[0] = packrne(e[0], e[1]);
      ue.u[1] = packrne(e[2], e[3]);
      pf[h] = ue.s;
    }

    // PV: O^T += V^T·P^T
    // vf = V^T[vcol=l15+16nt][kv chunk c=4h+quad] at slot (c + vcol/4)&15
    __builtin_amdgcn_s_setprio(1);
#pragma unroll
    for (int nt = 0; nt < 4; ++nt) {
      const int vcol = l15 + 16 * nt;
      const int xr   = (l15 >> 2) + 4 * nt;
#pragma unroll
      for (int h = 0; h < 4; ++h) {
        const int slot = ((4 * h + quad) + xr) & 15;
        short4v vf = *(const short4v*)&ldsV[p][vcol * VSTR + slot * 4];
        acc[nt] = mfma16(vf, pf[h], acc[nt]);
      }
    }
    __builtin_amdgcn_s_setprio(0);

    __syncthreads();   // drains DMA (vmcnt) + orders buffer reuse
  }

  // epilogue: single cross-quad reduce for the row sum
  rs += __shfl_xor(rs, 16, 64);
  rs += __shfl_xor(rs, 32, 64);

  if (Lb) {
    const size_t NSV = (size_t)N_B * S_Q * DH;
    float* ob = Ob + (size_t)z * NSV + ((size_t)n * S_Q + (size_t)qrow) * DH
              + quad * 4;
#pragma unroll
    for (int nt = 0; nt < 4; ++nt) *(f32x4*)(ob + 16 * nt) = acc[nt];
    if (quad == 0) {
      float* lp = Lb + (size_t)z * ((size_t)N_B * S_Q) + (size_t)n * S_Q
                + (size_t)qrow;
      lp[0] = rs;
    }
  } else {
    const float inv = 1.0f / rs;
    float* ob = Ob + ((size_t)n * S_Q + (size_t)qrow) * DH + quad * 4;
#pragma unroll
    for (int nt = 0; nt < 4; ++nt) {
      f32x4 o;
#pragma unroll
      for (int r = 0; r < 4; ++r) o[r] = acc[nt][r] * inv;
      *(f32x4*)(ob + 16 * nt) = o;
    }
  }
}

// ---- ultimate fallback: v13 reg-staging single-pass (proven r8, 56 VGPR)
__global__ __launch_bounds__(512, 4)
void sdpa_fwd_reg(const float* __restrict__ Qg, const float* __restrict__ Kg,
                  const float* __restrict__ Vg, const float* __restrict__ Mg,
                  float* __restrict__ Og)
{
  __shared__ __align__(16) unsigned short ldsK[2][BK * KSTR];
  __shared__ __align__(16) unsigned short ldsV[2][DH * VSTR];

  const int n = blockIdx.y, q0 = blockIdx.x * BQ, t = threadIdx.x;
  const int w = t >> 6, lane = t & 63, l15 = lane & 15, quad = lane >> 4;
  const int qrow = q0 + w * 16 + l15;

  short8 qf0, qf1;
  {
    const float* qp = Qg + ((size_t)n * S_Q + (size_t)qrow) * DH + quad * 8;
#pragma unroll
    for (int j = 0; j < 8; ++j) {
      qf0[j] = (short)f2bf(qp[j] * QSCALE);
      qf1[j] = (short)f2bf(qp[32 + j] * QSCALE);
    }
  }
  const bool isK = (w < 4);
  const int  tS  = t & 255;
  const float* sgp =
      isK ? Kg + ((size_t)n * S_KV + (size_t)(tS >> 3)) * DH + (tS & 7) * 8
          : Vg + ((size_t)n * S_KV + (size_t)(tS >> 4) * 4) * DH + (tS & 15) * 4;
  const float* mrow = Mg + (size_t)qrow * S_KV + quad * 4;

  f32x4 acc[4];
#pragma unroll
  for (int nt = 0; nt < 4; ++nt)
#pragma unroll
    for (int r = 0; r < 4; ++r) acc[nt][r] = 0.0f;
  float rs = 0.0f;

  {
    f32x4 L[4];
    if (isK) {
      L[0] = *(const f32x4*)(sgp);
      L[1] = *(const f32x4*)(sgp + 4);
      L[2] = *(const f32x4*)(sgp + 32 * DH);
      L[3] = *(const f32x4*)(sgp + 32 * DH + 4);
      stageK(&ldsK[0][0], L, tS);
    } else {
#pragma unroll
      for (int i = 0; i < 4; ++i) L[i] = *(const f32x4*)(sgp + i * DH);
      stageV(&ldsV[0][0], L, tS);
    }
  }
  __syncthreads();

  for (int it = 0; it < ITERS; ++it) {
    const int p = it & 1, kv0 = it * BK;
    const bool more = (it + 1 < ITERS);
    short4v pf[4];
#pragma unroll
    for (int h = 0; h < 4; ++h) {
      const short8 kf0 =
          *(const short8*)&ldsK[p][(l15 + 16 * h) * KSTR + quad * 8];
      const short8 kf1 =
          *(const short8*)&ldsK[p][(l15 + 16 * h) * KSTR + (quad + 4) * 8];
      const f32x4 mk = *(const f32x4*)(mrow + kv0 + 16 * h);
      f32x4 c = {0.f, 0.f, 0.f, 0.f};
      c = __builtin_amdgcn_mfma_f32_16x16x32_bf16(kf0, qf0, c, 0, 0, 0);
      c = __builtin_amdgcn_mfma_f32_16x16x32_bf16(kf1, qf1, c, 0, 0, 0);
      float e[4];
#pragma unroll
      for (int r = 0; r < 4; ++r)
        e[r] = __builtin_amdgcn_exp2f(fmaf(mk[r], LOG2E, c[r]));
      rs += (e[0] + e[1]) + (e[2] + e[3]);
      union { uint2v u; short4v s; } ue;
      ue.u[0] = packrne(e[0], e[1]);
      ue.u[1] = packrne(e[2], e[3]);
      pf[h] = ue.s;
    }
    f32x4 L[4];
    if (more) {
      const float* np = sgp + (size_t)(kv0 + BK) * DH;
      if (isK) {
        L[0] = *(const f32x4*)(np);
        L[1] = *(const f32x4*)(np + 4);
        L[2] = *(const f32x4*)(np + 32 * DH);
        L[3] = *(const f32x4*)(np + 32 * DH + 4);
      } else {
#pragma unroll
        for (int i = 0; i < 4; ++i) L[i] = *(const f32x4*)(np + i * DH);
      }
    }
#pragma unroll
    for (int nt = 0; nt < 4; ++nt) {
      const int vcol = l15 + 16 * nt;
      const int xr   = (l15 >> 2) + 4 * nt;
#pragma unroll
      for (int h = 0; h < 4; ++h) {
        const int slot = ((4 * h + quad) + xr) & 15;
        short4v vf = *(const short4v*)&ldsV[p][vcol * VSTR + slot * 4];
        acc[nt] = mfma16(vf, pf[h], acc[nt]);
      }
    }
    if (more) {
      if (isK) stageK(&ldsK[p ^ 1][0], L, tS);
      else     stageV(&ldsV[p ^ 1][0], L, tS);
    }
    __syncthreads();
  }

  rs += __shfl_xor(rs, 16, 64);
  rs += __shfl_xor(rs, 32, 64);
  const float inv = 1.0f / rs;
  float* ob = Og + ((size_t)n * S_Q + (size_t)qrow) * DH + quad * 4;
#pragma unroll
  for (int nt = 0; nt < 4; ++nt) {
    f32x4 o;
#pragma unroll
    for (int r = 0; r < 4; ++r) o[r] = acc[nt][r] * inv;
    *(f32x4*)(ob + 16 * nt) = o;
  }
}

// combine: O = (acc0 + acc1) / (l0 + l1); pure streaming, ~50 MB -> ~13 us
__global__ __launch_bounds__(256)
void sdpa_combine(const float* __restrict__ ws, float* __restrict__ Og) {
  constexpr size_t NSV = (size_t)N_B * S_Q * DH;
  constexpr size_t NS  = (size_t)N_B * S_Q;
  const size_t i = (size_t)blockIdx.x * 256 + threadIdx.x;  // f32x4 index
  const f32x4* A0 = (const f32x4*)ws;
  const f32x4* A1 = A0 + NSV / 4;
  const float* L0 = ws + 2 * NSV;
  const float* L1 = L0 + NS;
  const size_t qi = i >> 4;
  const f32x4 a = A0[i], b = A1[i];
  const float inv = 1.0f / (L0[qi] + L1[qi]);
  f32x4 o;
#pragma unroll
  for (int r = 0; r < 4; ++r) o[r] = (a[r] + b[r]) * inv;
  ((f32x4*)Og)[i] = o;
}

extern "C" void kernel_launch(void* const* d_in, const int* in_sizes, int n_in,
                              void* d_out, int out_size, void* d_ws, size_t ws_size,
                              hipStream_t stream) {
  (void)in_sizes; (void)n_in; (void)out_size;
  const float* q = (const float*)d_in[0];
  const float* k = (const float*)d_in[1];
  const float* v = (const float*)d_in[2];
  const float* m = (const float*)d_in[3];
  float* o = (float*)d_out;

  constexpr size_t NSV = (size_t)N_B * S_Q * DH;
  constexpr size_t NS  = (size_t)N_B * S_Q;
  constexpr size_t IMG_BYTES = (size_t)N_B * 64 * TILE_B;          // 18.87 MB
  constexpr size_t SPL_BYTES = (2 * NSV + 2 * NS) * sizeof(float); // 34.08 MB

  // r8-proven spill tripwire on the high-occupancy build
  static int use8 = -1;
  if (use8 < 0) {
    hipFuncAttributes attr{};
    use8 = 0;
    if (hipFuncGetAttributes(&attr,
            reinterpret_cast<const void*>(&sdpa_fwd_dma<8>)) == hipSuccess &&
        attr.localSizeBytes == 0)
      use8 = 1;
  }

  if (d_ws != nullptr && ws_size >= IMG_BYTES + SPL_BYTES && use8) {
    // Path A: images + KV-split x2 -> 4 blocks/CU
    unsigned short* imgs = (unsigned short*)d_ws;
    float* part = (float*)((char*)d_ws + IMG_BYTES);
    hipLaunchKernelGGL(sdpa_prep, dim3(N_B * 64), dim3(256), 0, stream,
                       k, v, imgs);
    dim3 grid(S_Q / BQ, N_B, 2);
    hipLaunchKernelGGL((sdpa_fwd_dma<8>), grid, dim3(512), 0, stream,
                       q, m, imgs, part, part + 2 * NSV, ITERS / 2);
    hipLaunchKernelGGL(sdpa_combine, dim3((unsigned)(NSV / 4 / 256)),
                       dim3(256), 0, stream, (const float*)part, o);
  } else if (d_ws != nullptr && ws_size >= IMG_BYTES) {
    // Path B: images + single-pass DMA (2 blocks/CU)
    unsigned short* imgs = (unsigned short*)d_ws;
    hipLaunchKernelGGL(sdpa_prep, dim3(N_B * 64), dim3(256), 0, stream,
                       k, v, imgs);
    dim3 grid(S_Q / BQ, N_B, 1);
    hipLaunchKernelGGL((sdpa_fwd_dma<4>), grid, dim3(512), 0, stream,
                       q, m, imgs, o, (float*)nullptr, ITERS);
  } else {
    // Path C: proven v13 reg-staging single-pass
    dim3 grid(S_Q / BQ, N_B);
    hipLaunchKernelGGL(sdpa_fwd_reg, grid, dim3(512), 0, stream,
                       q, k, v, m, o);
  }
}